// Round 1
// baseline (99.866 us; speedup 1.0000x reference)
//
#include <hip/hip_runtime.h>

#define CONVEX_WEIGHT 0.1f

// Comparator: is angle(a) < angle(b), where angle = atan2(y, x) in (-pi, pi]?
// atan2 < 0  <=>  y < 0 (y==0 gives 0 or +pi, both >= 0).
// Within the same half-plane group, angular span < ~pi, so cross(a,b) > 0
// <=> angle(a) < angle(b). Exact for non-degenerate (measure-zero ties).
__device__ __forceinline__ bool ang_less(float ax, float ay, float bx, float by) {
    bool ha = ay < 0.0f;
    bool hb = by < 0.0f;
    if (ha != hb) return ha;           // negative-angle group sorts first
    return (ax * by - ay * bx) > 0.0f; // CCW from a to b => a has smaller angle
}

__device__ __forceinline__ void sort_ccw(float* sx, float* sy) {
    // 5-compare sorting network for 4 elements (ascending by angle).
#define CE_(i, j)                                                        \
    if (ang_less(sx[j], sy[j], sx[i], sy[i])) {                          \
        float t0 = sx[i]; sx[i] = sx[j]; sx[j] = t0;                     \
        float t1 = sy[i]; sy[i] = sy[j]; sy[j] = t1;                     \
    }
    CE_(0, 1) CE_(2, 3) CE_(0, 2) CE_(1, 3) CE_(1, 2)
#undef CE_
}

__global__ __launch_bounds__(256) void mgiou2dplus_kernel(
    const float4* __restrict__ pred4,
    const float4* __restrict__ targ4,
    float* __restrict__ out,
    int B)
{
    int b = blockIdx.x * blockDim.x + threadIdx.x;
    if (b >= B) return;

    // ---- load (element = 8 floats = 2 aligned float4) ----
    float4 pa = pred4[2 * b];
    float4 pb = pred4[2 * b + 1];
    float4 ta = targ4[2 * b];
    float4 tb = targ4[2 * b + 1];

    float px[4] = { pa.x, pa.z, pb.x, pb.z };
    float py[4] = { pa.y, pa.w, pb.y, pb.w };
    float tx[4] = { ta.x, ta.z, tb.x, tb.z };
    float ty[4] = { ta.y, ta.w, tb.y, tb.w };

    // ---- centers and centered coords ----
    float pcx = (px[0] + px[1] + px[2] + px[3]) * 0.25f;
    float pcy = (py[0] + py[1] + py[2] + py[3]) * 0.25f;
    float tcx = (tx[0] + tx[1] + tx[2] + tx[3]) * 0.25f;
    float tcy = (ty[0] + ty[1] + ty[2] + ty[3]) * 0.25f;

    float rpx[4], rpy[4], rtx[4], rty[4];
#pragma unroll
    for (int i = 0; i < 4; ++i) {
        rpx[i] = px[i] - pcx;  rpy[i] = py[i] - pcy;
        rtx[i] = tx[i] - tcx;  rty[i] = ty[i] - tcy;
    }

    // ---- sort by angle around center (cyclic order; edges are center-invariant) ----
    sort_ccw(rpx, rpy);
    sort_ccw(rtx, rty);

    // ---- candidate axes: normals of sorted edges (4 from pred, 4 from target) ----
    float axx[8], axy[8];
#pragma unroll
    for (int i = 0; i < 4; ++i) {
        int j = (i + 1) & 3;
        float ex = rpx[j] - rpx[i];
        float ey = rpy[j] - rpy[i];
        axx[i] = ey;  axy[i] = -ex;     // normal = (edge.y, -edge.x)
        ex = rtx[j] - rtx[i];
        ey = rty[j] - rty[i];
        axx[4 + i] = ey;  axy[4 + i] = -ex;
    }

    // ---- per-axis 1D GIoU (absolute-coordinate projections) ----
    float gsum = 0.0f;
#pragma unroll
    for (int a = 0; a < 8; ++a) {
        float nx = axx[a], ny = axy[a];

        float q = px[0] * nx + py[0] * ny;
        float mn1 = q, mx1 = q;
        q = px[1] * nx + py[1] * ny; mn1 = fminf(mn1, q); mx1 = fmaxf(mx1, q);
        q = px[2] * nx + py[2] * ny; mn1 = fminf(mn1, q); mx1 = fmaxf(mx1, q);
        q = px[3] * nx + py[3] * ny; mn1 = fminf(mn1, q); mx1 = fmaxf(mx1, q);

        q = tx[0] * nx + ty[0] * ny;
        float mn2 = q, mx2 = q;
        q = tx[1] * nx + ty[1] * ny; mn2 = fminf(mn2, q); mx2 = fmaxf(mx2, q);
        q = tx[2] * nx + ty[2] * ny; mn2 = fminf(mn2, q); mx2 = fmaxf(mx2, q);
        q = tx[3] * nx + ty[3] * ny; mn2 = fminf(mn2, q); mx2 = fmaxf(mx2, q);

        float inter = fmaxf(fminf(mx1, mx2) - fmaxf(mn1, mn2), 0.0f);
        float uni   = (mx1 - mn1) + (mx2 - mn2) - inter;
        float hull  = fmaxf(mx1, mx2) - fminf(mn1, mn2);
        gsum += __fdividef(inter, uni) - __fdividef(hull - uni, hull);
    }

    float loss = (1.0f - gsum * 0.125f) * 0.5f;

    // ---- convexity penalty on pred (original vertex order) ----
    float cr[4];
#pragma unroll
    for (int i = 0; i < 4; ++i) {
        int ip = (i + 3) & 3;
        int in_ = (i + 1) & 3;
        float e1x = px[ip] - px[i], e1y = py[ip] - py[i];
        float e2x = px[in_] - px[i], e2y = py[in_] - py[i];
        cr[i] = e1x * e2y - e1y * e2x;
    }
    // sign_ref = sign(c0) with c0==0 -> +1
    float sref = (cr[0] < 0.0f) ? -1.0f : 1.0f;
    float pen = 0.0f;
#pragma unroll
    for (int i = 0; i < 4; ++i)
        pen += fmaxf(-sref * cr[i], 0.0f);

    loss += CONVEX_WEIGHT * (pen * 0.25f);

    out[b] = loss;
}

extern "C" void kernel_launch(void* const* d_in, const int* in_sizes, int n_in,
                              void* d_out, int out_size, void* d_ws, size_t ws_size,
                              hipStream_t stream)
{
    const float4* pred = (const float4*)d_in[0];
    const float4* targ = (const float4*)d_in[1];
    float* out = (float*)d_out;
    int B = in_sizes[0] / 8;   // (B, 4, 2) floats

    const int threads = 256;
    int blocks = (B + threads - 1) / threads;
    mgiou2dplus_kernel<<<blocks, threads, 0, stream>>>(pred, targ, out, B);
}

// Round 2
// 97.181 us; speedup vs baseline: 1.0276x; 1.0276x over previous
//
#include <hip/hip_runtime.h>

#define CONVEX_WEIGHT 0.1f

// Branchless compare-exchange on (ax,ay),(bx,by) by angle = atan2(y,x) in (-pi,pi].
// atan2 < 0 <=> y < 0. Same half-plane: span < pi, so cross(a,b)>0 <=> ang(a)<ang(b).
// All selects -> v_cndmask, no control flow, no address-taken arrays (SROA-safe).
#define ANG_CE(ax, ay, bx, by)                                            \
    {                                                                     \
        bool ha = (ay) < 0.0f;                                            \
        bool hb = (by) < 0.0f;                                            \
        float cr_ = (ax) * (by) - (ay) * (bx);                            \
        bool a_first = (ha == hb) ? (cr_ > 0.0f) : ha;                    \
        float t;                                                          \
        t = a_first ? (ax) : (bx); (bx) = a_first ? (bx) : (ax); (ax) = t;\
        t = a_first ? (ay) : (by); (by) = a_first ? (by) : (ay); (ay) = t;\
    }

__global__ __launch_bounds__(256) void mgiou2dplus_kernel(
    const float4* __restrict__ pred4,
    const float4* __restrict__ targ4,
    float* __restrict__ out,
    int B)
{
    int b = blockIdx.x * blockDim.x + threadIdx.x;
    if (b >= B) return;

    // ---- load (element = 8 floats = 2 aligned float4) ----
    float4 pa = pred4[2 * b];
    float4 pb = pred4[2 * b + 1];
    float4 ta = targ4[2 * b];
    float4 tb = targ4[2 * b + 1];

    float px0 = pa.x, py0 = pa.y, px1 = pa.z, py1 = pa.w;
    float px2 = pb.x, py2 = pb.y, px3 = pb.z, py3 = pb.w;
    float tx0 = ta.x, ty0 = ta.y, tx1 = ta.z, ty1 = ta.w;
    float tx2 = tb.x, ty2 = tb.y, tx3 = tb.z, ty3 = tb.w;

    // ---- centers, centered coords ----
    float pcx = (px0 + px1 + px2 + px3) * 0.25f;
    float pcy = (py0 + py1 + py2 + py3) * 0.25f;
    float tcx = (tx0 + tx1 + tx2 + tx3) * 0.25f;
    float tcy = (ty0 + ty1 + ty2 + ty3) * 0.25f;

    float a0x = px0 - pcx, a0y = py0 - pcy;
    float a1x = px1 - pcx, a1y = py1 - pcy;
    float a2x = px2 - pcx, a2y = py2 - pcy;
    float a3x = px3 - pcx, a3y = py3 - pcy;

    float b0x = tx0 - tcx, b0y = ty0 - tcy;
    float b1x = tx1 - tcx, b1y = ty1 - tcy;
    float b2x = tx2 - tcx, b2y = ty2 - tcy;
    float b3x = tx3 - tcx, b3y = ty3 - tcy;

    // ---- 5-CE sorting network, ascending by angle (branchless) ----
    ANG_CE(a0x, a0y, a1x, a1y) ANG_CE(a2x, a2y, a3x, a3y)
    ANG_CE(a0x, a0y, a2x, a2y) ANG_CE(a1x, a1y, a3x, a3y)
    ANG_CE(a1x, a1y, a2x, a2y)

    ANG_CE(b0x, b0y, b1x, b1y) ANG_CE(b2x, b2y, b3x, b3y)
    ANG_CE(b0x, b0y, b2x, b2y) ANG_CE(b1x, b1y, b3x, b3y)
    ANG_CE(b1x, b1y, b2x, b2y)

    // ---- per-axis 1D GIoU; axis = normal(edge) = (ey, -ex) ----
    float gsum = 0.0f;

#define AXIS_GIOU(nx, ny)                                                  \
    {                                                                      \
        float nx_ = (nx), ny_ = (ny);                                      \
        float q = px0 * nx_ + py0 * ny_;                                   \
        float mn1 = q, mx1 = q;                                            \
        q = px1 * nx_ + py1 * ny_; mn1 = fminf(mn1, q); mx1 = fmaxf(mx1, q);\
        q = px2 * nx_ + py2 * ny_; mn1 = fminf(mn1, q); mx1 = fmaxf(mx1, q);\
        q = px3 * nx_ + py3 * ny_; mn1 = fminf(mn1, q); mx1 = fmaxf(mx1, q);\
        q = tx0 * nx_ + ty0 * ny_;                                         \
        float mn2 = q, mx2 = q;                                            \
        q = tx1 * nx_ + ty1 * ny_; mn2 = fminf(mn2, q); mx2 = fmaxf(mx2, q);\
        q = tx2 * nx_ + ty2 * ny_; mn2 = fminf(mn2, q); mx2 = fmaxf(mx2, q);\
        q = tx3 * nx_ + ty3 * ny_; mn2 = fminf(mn2, q); mx2 = fmaxf(mx2, q);\
        float inter = fmaxf(fminf(mx1, mx2) - fmaxf(mn1, mn2), 0.0f);      \
        float uni   = (mx1 - mn1) + (mx2 - mn2) - inter;                   \
        float hull  = fmaxf(mx1, mx2) - fminf(mn1, mn2);                   \
        /* inter/uni - (hull-uni)/hull == (inter*hull - (hull-uni)*uni) / (uni*hull) */ \
        gsum += __fdividef(inter * hull - (hull - uni) * uni, uni * hull); \
    }

    AXIS_GIOU(a1y - a0y, a0x - a1x)
    AXIS_GIOU(a2y - a1y, a1x - a2x)
    AXIS_GIOU(a3y - a2y, a2x - a3x)
    AXIS_GIOU(a0y - a3y, a3x - a0x)
    AXIS_GIOU(b1y - b0y, b0x - b1x)
    AXIS_GIOU(b2y - b1y, b1x - b2x)
    AXIS_GIOU(b3y - b2y, b2x - b3x)
    AXIS_GIOU(b0y - b3y, b3x - b0x)
#undef AXIS_GIOU

    float loss = (1.0f - gsum * 0.125f) * 0.5f;

    // ---- convexity penalty on pred (original vertex order) ----
    // cr[i] = cross(v[i-1]-v[i], v[i+1]-v[i])
    float c0, c1, c2, c3;
    {
        float e1x, e1y, e2x, e2y;
        e1x = px3 - px0; e1y = py3 - py0; e2x = px1 - px0; e2y = py1 - py0;
        c0 = e1x * e2y - e1y * e2x;
        e1x = px0 - px1; e1y = py0 - py1; e2x = px2 - px1; e2y = py2 - py1;
        c1 = e1x * e2y - e1y * e2x;
        e1x = px1 - px2; e1y = py1 - py2; e2x = px3 - px2; e2y = py3 - py2;
        c2 = e1x * e2y - e1y * e2x;
        e1x = px2 - px3; e1y = py2 - py3; e2x = px0 - px3; e2y = py0 - py3;
        c3 = e1x * e2y - e1y * e2x;
    }
    float sref = (c0 < 0.0f) ? -1.0f : 1.0f;   // sign(c0), 0 -> +1
    float pen = fmaxf(-sref * c0, 0.0f) + fmaxf(-sref * c1, 0.0f)
              + fmaxf(-sref * c2, 0.0f) + fmaxf(-sref * c3, 0.0f);

    loss += CONVEX_WEIGHT * (pen * 0.25f);

    out[b] = loss;
}

extern "C" void kernel_launch(void* const* d_in, const int* in_sizes, int n_in,
                              void* d_out, int out_size, void* d_ws, size_t ws_size,
                              hipStream_t stream)
{
    const float4* pred = (const float4*)d_in[0];
    const float4* targ = (const float4*)d_in[1];
    float* out = (float*)d_out;
    int B = in_sizes[0] / 8;   // (B, 4, 2) floats

    const int threads = 256;
    int blocks = (B + threads - 1) / threads;
    mgiou2dplus_kernel<<<blocks, threads, 0, stream>>>(pred, targ, out, B);
}